// Round 8
// baseline (128.582 us; speedup 1.0000x reference)
//
#include <hip/hip_runtime.h>
#include <hip/hip_bf16.h>

#define B_ 16
#define S_ 512
#define E_ 256
#define H_ 4
#define D_ 64
#define L_ 2
#define MAXPOS 10
#define HS_ ((size_t)B_ * S_ * E_)

typedef __attribute__((ext_vector_type(8))) short bf16x8;
typedef __attribute__((ext_vector_type(4))) float f32x4;

static __device__ __forceinline__ short f2bf(float f) {
    __hip_bfloat16 h = __float2bfloat16(f);
    return __builtin_bit_cast(short, h);
}

static __device__ __forceinline__ void gload16(const void* g, void* l) {
    __builtin_amdgcn_global_load_lds(
        (const __attribute__((address_space(1))) void*)(g),
        (__attribute__((address_space(3))) void*)(l),
        16, 0, 0);
}

// stage a 32 KB contiguous global tile into LDS, XOR-swizzled:
// LDS[r*512 + c] = G[r*512 + (c ^ ((r&7)<<4))]
static __device__ __forceinline__ void stage_tile(const char* gbase, char* lds,
                                                  int w, int lane) {
    #pragma unroll
    for (int c = 0; c < 8; ++c) {
        const int L = (w * 8 + c) * 1024 + lane * 16;
        const int src = L ^ (((L >> 9) & 7) << 4);
        gload16(gbase + src, lds + (w * 8 + c) * 1024);
    }
}

// 64x64 tile GEMM over K=256; accumulators are NAMED refs (rule #20: no
// register arrays -> no scratch).
static __device__ __forceinline__ void gemm4(const short* As, const short* Bs,
                                             int w, int l15, int l4,
                                             f32x4& a0, f32x4& a1,
                                             f32x4& a2, f32x4& a3) {
    const int sw = (l15 & 7) << 4;
    const int arow = w * 16 + l15;
    const f32x4 z4 = (f32x4){0.f, 0.f, 0.f, 0.f};
    a0 = z4; a1 = z4; a2 = z4; a3 = z4;
    #pragma unroll
    for (int ks = 0; ks < 8; ++ks) {
        const int coff = (ks * 64 + l4 * 16) ^ sw;
        const bf16x8 af = *reinterpret_cast<const bf16x8*>((const char*)As + arow * 512 + coff);
        const bf16x8 b0 = *reinterpret_cast<const bf16x8*>((const char*)Bs + (0 * 16 + l15) * 512 + coff);
        a0 = __builtin_amdgcn_mfma_f32_16x16x32_bf16(af, b0, a0, 0, 0, 0);
        const bf16x8 b1 = *reinterpret_cast<const bf16x8*>((const char*)Bs + (1 * 16 + l15) * 512 + coff);
        a1 = __builtin_amdgcn_mfma_f32_16x16x32_bf16(af, b1, a1, 0, 0, 0);
        const bf16x8 b2 = *reinterpret_cast<const bf16x8*>((const char*)Bs + (2 * 16 + l15) * 512 + coff);
        a2 = __builtin_amdgcn_mfma_f32_16x16x32_bf16(af, b2, a2, 0, 0, 0);
        const bf16x8 b3 = *reinterpret_cast<const bf16x8*>((const char*)Bs + (3 * 16 + l15) * 512 + coff);
        a3 = __builtin_amdgcn_mfma_f32_16x16x32_bf16(af, b3, a3, 0, 0, 0);
    }
}

// array-based wrapper for the simple kernels (their local acc[4] promotes fine)
static __device__ __forceinline__ void gemm_compute(const short* As, const short* Bs,
                                                    f32x4* acc, int w, int l15, int l4) {
    gemm4(As, Bs, w, l15, l4, acc[0], acc[1], acc[2], acc[3]);
}

// ---------------- setup: gather (16 rows/block) + Wt transpose + y init
__global__ __launch_bounds__(256) void setup_kernel(
    const int* __restrict__ item_inputs, const int* __restrict__ item_ids,
    const float* __restrict__ input_embed, const float* __restrict__ query_embed,
    const float* __restrict__ Wq, const float* __restrict__ Wk,
    const float* __restrict__ Wv, const float* __restrict__ Wo,
    const float* __restrict__ out_b,
    float* __restrict__ outf, short* __restrict__ outb, short* __restrict__ qbb,
    short* __restrict__ Wt, float* __restrict__ y)
{
    const int tid = threadIdx.x;
    const int bx = blockIdx.x;
    if (bx < 512) {
        const int rr = tid >> 4, c0 = (tid & 15) * 16;
        const int row = bx * 16 + rr;
        const int ii = item_inputs[row];
        const int qi = item_ids[row];
        const float* xs = input_embed + (size_t)ii * E_ + c0;
        const float* qs = query_embed + (size_t)qi * E_ + c0;
        float* of = outf + (size_t)row * E_ + c0;
        short* ob = outb + (size_t)row * E_ + c0;
        short* qb = qbb + (size_t)row * E_ + c0;
        #pragma unroll
        for (int q = 0; q < 4; ++q) {
            const float4 xv = reinterpret_cast<const float4*>(xs)[q];
            const float4 qv = reinterpret_cast<const float4*>(qs)[q];
            reinterpret_cast<float4*>(of)[q] = xv;
            short4 xb = { f2bf(xv.x), f2bf(xv.y), f2bf(xv.z), f2bf(xv.w) };
            short4 qb4 = { f2bf(qv.x), f2bf(qv.y), f2bf(qv.z), f2bf(qv.w) };
            reinterpret_cast<short4*>(ob)[q] = xb;
            reinterpret_cast<short4*>(qb)[q] = qb4;
        }
        return;
    }
    const int pb = bx - 512;
    if (pb < 128) {
        __shared__ short tt[64 * 72];
        const int mId = pb >> 4;
        const int l = mId >> 2, which = mId & 3;
        const float* src = (which == 0 ? Wq : which == 1 ? Wk : which == 2 ? Wv : Wo)
                         + (size_t)l * E_ * E_;
        const int tr = (pb >> 2) & 3;
        const int tc = pb & 3;
        {
            const int kl = tid >> 2;
            const int nq = (tid & 3) * 16;
            const float* sp = src + (size_t)(tr * 64 + kl) * E_ + tc * 64 + nq;
            #pragma unroll
            for (int q = 0; q < 4; ++q) {
                const float4 v = reinterpret_cast<const float4*>(sp)[q];
                tt[(nq + q * 4 + 0) * 72 + kl] = f2bf(v.x);
                tt[(nq + q * 4 + 1) * 72 + kl] = f2bf(v.y);
                tt[(nq + q * 4 + 2) * 72 + kl] = f2bf(v.z);
                tt[(nq + q * 4 + 3) * 72 + kl] = f2bf(v.w);
            }
        }
        __syncthreads();
        {
            const int nl = tid >> 2;
            const int kq = (tid & 3) * 16;
            short* dst = Wt + (size_t)mId * 65536 + (size_t)(tc * 64 + nl) * E_ + tr * 64 + kq;
            *reinterpret_cast<bf16x8*>(&dst[0]) = *reinterpret_cast<const bf16x8*>(&tt[nl * 72 + kq]);
            *reinterpret_cast<bf16x8*>(&dst[8]) = *reinterpret_cast<const bf16x8*>(&tt[nl * 72 + kq + 8]);
        }
    } else if (pb == 128) {
        const float yb = out_b[0];
        for (int i = tid; i < 8192; i += 256) y[i] = yb;
    }
}

// ---------------- layer-0 QKV: grid (128, 4, 3)
__global__ __launch_bounds__(256) void qkv0_kernel(
    const short* __restrict__ qbb, const short* __restrict__ outb,
    const short* __restrict__ Wt, const float* __restrict__ bq,
    const float* __restrict__ bk, const float* __restrict__ bv,
    short* __restrict__ Qb)
{
    __shared__ __align__(16) short As[64 * 256];
    __shared__ __align__(16) short Bs[64 * 256];
    const int bm = blockIdx.x, bn = blockIdx.y, z = blockIdx.z;
    const int tid = threadIdx.x;
    const int lane = tid & 63, w = tid >> 6;
    const int l15 = lane & 15, l4 = lane >> 4;

    const short* A = (z == 0) ? qbb : outb;
    const short* W = Wt + (size_t)z * 65536;
    const float* bias = (z == 0) ? bq : (z == 1) ? bk : bv;

    stage_tile((const char*)A + (size_t)bm * 32768, (char*)As, w, lane);
    stage_tile((const char*)W + (size_t)bn * 32768, (char*)Bs, w, lane);
    __syncthreads();

    f32x4 acc[4];
    gemm_compute(As, Bs, acc, w, l15, l4);

    short* Cz = Qb + (size_t)z * HS_;
    #pragma unroll
    for (int nf = 0; nf < 4; ++nf) {
        const int col = bn * 64 + nf * 16 + l15;
        const float bb = bias[col];
        #pragma unroll
        for (int reg = 0; reg < 4; ++reg) {
            const int rowg = bm * 64 + w * 16 + l4 * 4 + reg;
            Cz[(size_t)rowg * E_ + col] = f2bf(acc[nf][reg] + bb);
        }
    }
}

// ---------------- paired flash attention: 256 blocks, q-tiles (7-a, a) per block
__global__ __launch_bounds__(256) void attn2_kernel(
    const short* __restrict__ Q, const short* __restrict__ K,
    const short* __restrict__ V, const float* __restrict__ pos_key,
    const float* __restrict__ pos_value, short* __restrict__ merged)
{
    __shared__ __align__(16) short Qs[64 * 72];
    __shared__ __align__(16) short Ks[64 * 64];
    __shared__ __align__(16) short Vts[4656];
    __shared__ __align__(16) short Pl[4 * 16 * 72];
    __shared__ __align__(16) short Pk[16 * 72];
    __shared__ float pv_sh[MAXPOS * 64];
    __shared__ float qpk_sh[64 * 16];
    __shared__ float pdiag[64 * 9];

    const int bid = blockIdx.x;
    const int a = bid & 3;
    const int h = (bid >> 2) & 3;
    const int b = bid >> 4;
    const int tid = threadIdx.x;
    const int lane = tid & 63;
    const int w = tid >> 6;
    const int l15 = lane & 15;
    const int l4  = lane >> 4;
    const int rloc  = l4 * 4;
    const int rbase = w * 16 + rloc;
    const int swl = (l15 & 7) << 4;

    const size_t boff = (size_t)(b * S_) * E_ + h * D_;

    for (int idx = tid; idx < MAXPOS * 64; idx += 256) pv_sh[idx] = pos_value[idx];
    for (int idx = tid; idx < 16 * 64; idx += 256) {
        const int r = idx >> 6, d = idx & 63;
        Pk[r * 72 + d] = (r < MAXPOS) ? f2bf(pos_key[r * 64 + d]) : (short)0;
    }

    for (int pass = 0; pass < 2; ++pass) {
        const int it = pass ? a : 7 - a;
        if (pass) __syncthreads();
        for (int idx = tid; idx < 64 * 9; idx += 256) pdiag[idx] = 0.0f;
        {
            const int row = tid >> 2, dq = (tid & 3) * 16;
            const short* qp = &Q[boff + (size_t)(it * 64 + row) * E_ + dq];
            *reinterpret_cast<bf16x8*>(&Qs[row * 72 + dq]) = *reinterpret_cast<const bf16x8*>(qp);
            *reinterpret_cast<bf16x8*>(&Qs[row * 72 + dq + 8]) = *reinterpret_cast<const bf16x8*>(qp + 8);
        }
        __syncthreads();

        bf16x8 aq[2];
        #pragma unroll
        for (int ks = 0; ks < 2; ++ks)
            aq[ks] = *reinterpret_cast<const bf16x8*>(&Qs[(w * 16 + l15) * 72 + ks * 32 + 8 * l4]);

        f32x4 cq = (f32x4){0.f, 0.f, 0.f, 0.f};
        #pragma unroll
        for (int ks = 0; ks < 2; ++ks) {
            const bf16x8 bpk = *reinterpret_cast<const bf16x8*>(&Pk[l15 * 72 + ks * 32 + 8 * l4]);
            cq = __builtin_amdgcn_mfma_f32_16x16x32_bf16(aq[ks], bpk, cq, 0, 0, 0);
        }
        float q9[4];
        #pragma unroll
        for (int r = 0; r < 4; ++r) {
            qpk_sh[(rbase + r) * 16 + l15] = cq[r] * 0.125f;
            q9[r] = __shfl(cq[r], l4 * 16 + 9, 64) * 0.125f;
        }

        f32x4 accv[4];
        #pragma unroll
        for (int nf = 0; nf < 4; ++nf) accv[nf] = (f32x4){0.f, 0.f, 0.f, 0.f};
        float ls[4] = {0.f, 0.f, 0.f, 0.f};

        for (int jt = 0; jt <= it; ++jt) {
            {
                const char* Kb = (const char*)(K + boff + (size_t)(jt * 64) * E_);
                #pragma unroll
                for (int c = 0; c < 2; ++c) {
                    const int chunk = w * 2 + c;
                    const int row = chunk * 8 + (lane >> 3);
                    const int col = (lane & 7) * 16;
                    const int src = row * 512 + (col ^ ((row & 7) << 4));
                    gload16(Kb + src, (char*)Ks + chunk * 1024);
                }
                const int row = tid >> 2, dq = (tid & 3) * 16;
                const short* vp = &V[boff + (size_t)(jt * 64 + row) * E_ + dq];
                const bf16x8 v0 = *reinterpret_cast<const bf16x8*>(vp);
                const bf16x8 v1 = *reinterpret_cast<const bf16x8*>(vp + 8);
                const int skew = (tid & 3) * 32 + row * 2;
                #pragma unroll
                for (int e = 0; e < 8; ++e) {
                    *(short*)((char*)Vts + (dq + e) * 144 + skew) = v0[e];
                    *(short*)((char*)Vts + (dq + 8 + e) * 144 + skew) = v1[e];
                }
            }
            __syncthreads();

            const bool near = (jt >= it - 1);
            #pragma unroll
            for (int nf = 0; nf < 4; ++nf) {
                f32x4 c = (f32x4){0.f, 0.f, 0.f, 0.f};
                const int jrow = nf * 16 + l15;
                const bf16x8 bk0 = *reinterpret_cast<const bf16x8*>(
                    (const char*)Ks + jrow * 128 + ((l4 * 16) ^ swl));
                const bf16x8 bk1 = *reinterpret_cast<const bf16x8*>(
                    (const char*)Ks + jrow * 128 + ((64 + l4 * 16) ^ swl));
                c = __builtin_amdgcn_mfma_f32_16x16x32_bf16(aq[0], bk0, c, 0, 0, 0);
                c = __builtin_amdgcn_mfma_f32_16x16x32_bf16(aq[1], bk1, c, 0, 0, 0);
                const int j = jt * 64 + nf * 16 + l15;
                #pragma unroll
                for (int r = 0; r < 4; ++r) {
                    float pp;
                    if (near) {
                        const int i = it * 64 + rbase + r;
                        const int rel = i - j;
                        if (rel < 0) pp = 0.0f;
                        else {
                            const int rc = rel < 9 ? rel : 9;
                            pp = __expf(fmaf(c[r], 0.125f, qpk_sh[(rbase + r) * 16 + rc]));
                            if (rel < 9) pdiag[(rbase + r) * 9 + rel] = pp;
                        }
                    } else {
                        pp = __expf(fmaf(c[r], 0.125f, q9[r]));
                    }
                    ls[r] += pp;
                    Pl[w * 1152 + (rloc + r) * 72 + nf * 16 + l15] = f2bf(pp);
                }
            }
            #pragma unroll
            for (int ks = 0; ks < 2; ++ks) {
                const bf16x8 pa = *reinterpret_cast<const bf16x8*>(
                    &Pl[w * 1152 + l15 * 72 + ks * 32 + 8 * l4]);
                #pragma unroll
                for (int nf = 0; nf < 4; ++nf) {
                    const int d = nf * 16 + l15;
                    const bf16x8 bv = *reinterpret_cast<const bf16x8*>(
                        (const char*)Vts + d * 144 + nf * 32 + ks * 64 + l4 * 16);
                    accv[nf] = __builtin_amdgcn_mfma_f32_16x16x32_bf16(pa, bv, accv[nf], 0, 0, 0);
                }
            }
            __syncthreads();
        }

        #pragma unroll
        for (int m = 1; m < 16; m <<= 1) {
            #pragma unroll
            for (int r = 0; r < 4; ++r) ls[r] += __shfl_xor(ls[r], m, 64);
        }

        #pragma unroll
        for (int r = 0; r < 4; ++r) {
            const int rowl = rbase + r;
            const float inv = 1.0f / ls[r];
            #pragma unroll
            for (int nf = 0; nf < 4; ++nf) {
                const int col = nf * 16 + l15;
                const float pv9 = pv_sh[9 * 64 + col];
                float extra = ls[r] * pv9;
                #pragma unroll
                for (int rr = 0; rr < 9; ++rr)
                    extra += pdiag[rowl * 9 + rr] * (pv_sh[rr * 64 + col] - pv9);
                merged[boff + (size_t)(it * 64 + rowl) * E_ + col] =
                    f2bf((accv[nf][r] + extra) * inv);
            }
        }
    }
}

// ---------------- fused O-proj(layer0) + QKV(layer1): 128 blocks
// Accumulators are 16 NAMED f32x4 vars (no arrays -> no scratch, rule #20).
#define EPI(BN, NF, ACC)                                                      \
    do {                                                                      \
        const int col = (BN) * 64 + (NF) * 16 + l15;                          \
        const float bb = bo0[col];                                            \
        _Pragma("unroll")                                                     \
        for (int reg = 0; reg < 4; ++reg) {                                   \
            const int row = w * 16 + l4 * 4 + reg;                            \
            const size_t gidx = (size_t)(bm * 64 + row) * E_ + col;           \
            const float o = outf[gidx] + fmaxf((ACC)[reg] + bb, 0.0f);        \
            outf[gidx] = o;                                                   \
            *(short*)((char*)Xs + row * 512 + ((2 * col) ^ ((row & 7) << 4))) \
                = f2bf(o);                                                    \
        }                                                                     \
    } while (0)

__global__ __launch_bounds__(256) void oqkv_kernel(
    const short* __restrict__ qbb, const short* __restrict__ mgb,
    const short* __restrict__ Wt, const float* __restrict__ bo0,
    const float* __restrict__ bq1, const float* __restrict__ bk1,
    const float* __restrict__ bv1, float* __restrict__ outf,
    short* __restrict__ Qb)
{
    __shared__ __align__(16) short Qs2[64 * 256];
    __shared__ __align__(16) short Xs[64 * 256];
    __shared__ __align__(16) short Bs[2][64 * 256];
    const int bm = blockIdx.x;
    const int tid = threadIdx.x, lane = tid & 63, w = tid >> 6;
    const int l15 = lane & 15, l4 = lane >> 4;

    stage_tile((const char*)qbb + (size_t)bm * 32768, (char*)Qs2, w, lane);
    stage_tile((const char*)mgb + (size_t)bm * 32768, (char*)Xs, w, lane);
    stage_tile((const char*)(Wt + 3 * 65536), (char*)Bs[0], w, lane);   // Wo0 bn=0

    // ---- Phase O: 4 tiles, hand-unrolled, named accumulators
    f32x4 o00, o01, o02, o03, o10, o11, o12, o13;
    f32x4 o20, o21, o22, o23, o30, o31, o32, o33;

    __syncthreads();
    stage_tile((const char*)(Wt + 3 * 65536 + 1 * 16384), (char*)Bs[1], w, lane);
    gemm4(Xs, Bs[0], w, l15, l4, o00, o01, o02, o03);

    __syncthreads();
    stage_tile((const char*)(Wt + 3 * 65536 + 2 * 16384), (char*)Bs[0], w, lane);
    gemm4(Xs, Bs[1], w, l15, l4, o10, o11, o12, o13);

    __syncthreads();
    stage_tile((const char*)(Wt + 3 * 65536 + 3 * 16384), (char*)Bs[1], w, lane);
    gemm4(Xs, Bs[0], w, l15, l4, o20, o21, o22, o23);

    __syncthreads();
    stage_tile((const char*)(Wt + 4 * 65536), (char*)Bs[0], w, lane);   // Wq1 bn=0
    gemm4(Xs, Bs[1], w, l15, l4, o30, o31, o32, o33);

    __syncthreads();   // all waves done reading Xs (as mgb tile)

    // ---- epilogue: relu + residual -> outf (f32) and Xs (bf16, swizzled)
    EPI(0, 0, o00); EPI(0, 1, o01); EPI(0, 2, o02); EPI(0, 3, o03);
    EPI(1, 0, o10); EPI(1, 1, o11); EPI(1, 2, o12); EPI(1, 3, o13);
    EPI(2, 0, o20); EPI(2, 1, o21); EPI(2, 2, o22); EPI(2, 3, o23);
    EPI(3, 0, o30); EPI(3, 1, o31); EPI(3, 2, o32); EPI(3, 3, o33);

    // ---- Phase QKV: 12 tiles (z = q,k,v; bn = 0..3), fresh named accs per tile
    #pragma unroll
    for (int t = 4; t < 16; ++t) {
        __syncthreads();                       // Xs writes visible + vmcnt drained
        if (t + 1 < 16) {
            const int tn = t + 1;
            const size_t off = (size_t)(4 + ((tn - 4) >> 2)) * 65536
                             + (size_t)((tn - 4) & 3) * 16384;
            stage_tile((const char*)(Wt + off), (char*)Bs[tn & 1], w, lane);
        }
        const int z = (t - 4) >> 2, bn = (t - 4) & 3;
        f32x4 a0, a1, a2, a3;
        gemm4((z == 0) ? Qs2 : Xs, Bs[t & 1], w, l15, l4, a0, a1, a2, a3);
        const float* bias = (z == 0) ? bq1 : (z == 1) ? bk1 : bv1;
        short* Cz = Qb + (size_t)z * HS_;
        #pragma unroll
        for (int reg = 0; reg < 4; ++reg) {
            const int rowg = bm * 64 + w * 16 + l4 * 4 + reg;
            short* crow = Cz + (size_t)rowg * E_ + bn * 64;
            crow[0 * 16 + l15] = f2bf(a0[reg] + bias[bn * 64 + 0 * 16 + l15]);
            crow[1 * 16 + l15] = f2bf(a1[reg] + bias[bn * 64 + 1 * 16 + l15]);
            crow[2 * 16 + l15] = f2bf(a2[reg] + bias[bn * 64 + 2 * 16 + l15]);
            crow[3 * 16 + l15] = f2bf(a3[reg] + bias[bn * 64 + 3 * 16 + l15]);
        }
    }
}

// ---------------- last O-proj + final dot: grid (128, 4); y += per-block partials
__global__ __launch_bounds__(256) void o1final_kernel(
    const short* __restrict__ mgb, const short* __restrict__ Wt7,
    const float* __restrict__ bo1, const float* __restrict__ outf,
    const float* __restrict__ fw, float* __restrict__ y)
{
    __shared__ __align__(16) short As[64 * 256];
    __shared__ __align__(16) short Bs[64 * 256];
    const int bm = blockIdx.x, bn = blockIdx.y;
    const int tid = threadIdx.x;
    const int lane = tid & 63, w = tid >> 6;
    const int l15 = lane & 15, l4 = lane >> 4;

    stage_tile((const char*)mgb + (size_t)bm * 32768, (char*)As, w, lane);
    stage_tile((const char*)(Wt7 + (size_t)bn * 16384), (char*)Bs, w, lane);
    __syncthreads();

    f32x4 acc[4];
    gemm_compute(As, Bs, acc, w, l15, l4);

    float s[4] = {0.f, 0.f, 0.f, 0.f};
    #pragma unroll
    for (int nf = 0; nf < 4; ++nf) {
        const int col = bn * 64 + nf * 16 + l15;
        const float bb = bo1[col];
        const float fwv = fw[col];
        #pragma unroll
        for (int reg = 0; reg < 4; ++reg) {
            const int rowg = bm * 64 + w * 16 + l4 * 4 + reg;
            const float o = outf[(size_t)rowg * E_ + col] + fmaxf(acc[nf][reg] + bb, 0.0f);
            s[reg] += o * fwv;
        }
    }
    #pragma unroll
    for (int m = 1; m < 16; m <<= 1) {
        #pragma unroll
        for (int reg = 0; reg < 4; ++reg) s[reg] += __shfl_xor(s[reg], m, 64);
    }
    if (l15 == 0) {
        #pragma unroll
        for (int reg = 0; reg < 4; ++reg)
            atomicAdd(&y[bm * 64 + w * 16 + l4 * 4 + reg], s[reg]);
    }
}

extern "C" void kernel_launch(void* const* d_in, const int* in_sizes, int n_in,
                              void* d_out, int out_size, void* d_ws, size_t ws_size,
                              hipStream_t stream) {
    const int*   item_inputs = (const int*)d_in[0];
    const int*   item_ids    = (const int*)d_in[1];
    const float* input_embed = (const float*)d_in[2];
    const float* query_embed = (const float*)d_in[3];
    const float* pos_key     = (const float*)d_in[4];
    const float* pos_value   = (const float*)d_in[5];
    const float* Wq = (const float*)d_in[6];
    const float* bq = (const float*)d_in[7];
    const float* Wk = (const float*)d_in[8];
    const float* bk = (const float*)d_in[9];
    const float* Wv = (const float*)d_in[10];
    const float* bv = (const float*)d_in[11];
    const float* Wo = (const float*)d_in[12];
    const float* bo = (const float*)d_in[13];
    const float* out_w = (const float*)d_in[14];
    const float* out_b = (const float*)d_in[15];
    float* y = (float*)d_out;

    char* w8 = (char*)d_ws;
    float* outf = (float*)(w8);                          // 8 MB f32 hidden
    short* outb = (short*)(w8 + ((size_t)8  << 20));     // 4 MB bf16 hidden (layer0 KV input)
    short* qbb  = (short*)(w8 + ((size_t)12 << 20));     // 4 MB bf16 q-base
    short* Qb   = (short*)(w8 + ((size_t)16 << 20));     // 12 MB bf16 Q,K,V
    short* mgb  = (short*)(w8 + ((size_t)28 << 20));     // 4 MB bf16 merged
    short* Wt   = (short*)(w8 + ((size_t)32 << 20));     // 1 MB bf16 weights^T

    setup_kernel<<<641, 256, 0, stream>>>(
        item_inputs, item_ids, input_embed, query_embed,
        Wq, Wk, Wv, Wo, out_b, outf, outb, qbb, Wt, y);

    qkv0_kernel<<<dim3(128, 4, 3), 256, 0, stream>>>(
        qbb, outb, Wt, bq, bk, bv, Qb);

    attn2_kernel<<<256, 256, 0, stream>>>(
        Qb, Qb + HS_, Qb + 2 * HS_, pos_key, pos_value, mgb);

    oqkv_kernel<<<128, 256, 0, stream>>>(
        qbb, mgb, Wt, bo, bq + E_, bk + E_, bv + E_, outf, Qb);

    attn2_kernel<<<256, 256, 0, stream>>>(
        Qb, Qb + HS_, Qb + 2 * HS_, pos_key, pos_value, mgb);

    o1final_kernel<<<dim3(128, 4), 256, 0, stream>>>(
        mgb, Wt + (size_t)7 * 65536, bo + E_, outf, out_w, y);
}

// Round 9
// 112.225 us; speedup vs baseline: 1.1457x; 1.1457x over previous
//
#include <hip/hip_runtime.h>
#include <hip/hip_bf16.h>

#define B_ 16
#define S_ 512
#define E_ 256
#define H_ 4
#define D_ 64
#define L_ 2
#define MAXPOS 10
#define HS_ ((size_t)B_ * S_ * E_)

typedef __attribute__((ext_vector_type(8))) short bf16x8;
typedef __attribute__((ext_vector_type(4))) float f32x4;

static __device__ __forceinline__ short f2bf(float f) {
    __hip_bfloat16 h = __float2bfloat16(f);
    return __builtin_bit_cast(short, h);
}

static __device__ __forceinline__ void gload16(const void* g, void* l) {
    __builtin_amdgcn_global_load_lds(
        (const __attribute__((address_space(1))) void*)(g),
        (__attribute__((address_space(3))) void*)(l),
        16, 0, 0);
}

// stage a 32 KB contiguous global tile into LDS, XOR-swizzled:
// LDS[r*512 + c] = G[r*512 + (c ^ ((r&7)<<4))]
static __device__ __forceinline__ void stage_tile(const char* gbase, char* lds,
                                                  int w, int lane) {
    #pragma unroll
    for (int c = 0; c < 8; ++c) {
        const int L = (w * 8 + c) * 1024 + lane * 16;
        const int src = L ^ (((L >> 9) & 7) << 4);
        gload16(gbase + src, lds + (w * 8 + c) * 1024);
    }
}

// 64x64 tile GEMM over K=256; named accumulator refs (rule #20).
static __device__ __forceinline__ void gemm4(const short* As, const short* Bs,
                                             int w, int l15, int l4,
                                             f32x4& a0, f32x4& a1,
                                             f32x4& a2, f32x4& a3) {
    const int sw = (l15 & 7) << 4;
    const int arow = w * 16 + l15;
    const f32x4 z4 = (f32x4){0.f, 0.f, 0.f, 0.f};
    a0 = z4; a1 = z4; a2 = z4; a3 = z4;
    #pragma unroll
    for (int ks = 0; ks < 8; ++ks) {
        const int coff = (ks * 64 + l4 * 16) ^ sw;
        const bf16x8 af = *reinterpret_cast<const bf16x8*>((const char*)As + arow * 512 + coff);
        const bf16x8 b0 = *reinterpret_cast<const bf16x8*>((const char*)Bs + (0 * 16 + l15) * 512 + coff);
        a0 = __builtin_amdgcn_mfma_f32_16x16x32_bf16(af, b0, a0, 0, 0, 0);
        const bf16x8 b1 = *reinterpret_cast<const bf16x8*>((const char*)Bs + (1 * 16 + l15) * 512 + coff);
        a1 = __builtin_amdgcn_mfma_f32_16x16x32_bf16(af, b1, a1, 0, 0, 0);
        const bf16x8 b2 = *reinterpret_cast<const bf16x8*>((const char*)Bs + (2 * 16 + l15) * 512 + coff);
        a2 = __builtin_amdgcn_mfma_f32_16x16x32_bf16(af, b2, a2, 0, 0, 0);
        const bf16x8 b3 = *reinterpret_cast<const bf16x8*>((const char*)Bs + (3 * 16 + l15) * 512 + coff);
        a3 = __builtin_amdgcn_mfma_f32_16x16x32_bf16(af, b3, a3, 0, 0, 0);
    }
}

static __device__ __forceinline__ void gemm_compute(const short* As, const short* Bs,
                                                    f32x4* acc, int w, int l15, int l4) {
    gemm4(As, Bs, w, l15, l4, acc[0], acc[1], acc[2], acc[3]);
}

// ---------------- setup: gather (16 rows/block) + Wt transpose + y init
__global__ __launch_bounds__(256) void setup_kernel(
    const int* __restrict__ item_inputs, const int* __restrict__ item_ids,
    const float* __restrict__ input_embed, const float* __restrict__ query_embed,
    const float* __restrict__ Wq, const float* __restrict__ Wk,
    const float* __restrict__ Wv, const float* __restrict__ Wo,
    const float* __restrict__ out_b,
    float* __restrict__ outf, short* __restrict__ outb, short* __restrict__ qbb,
    short* __restrict__ Wt, float* __restrict__ y)
{
    const int tid = threadIdx.x;
    const int bx = blockIdx.x;
    if (bx < 512) {
        const int rr = tid >> 4, c0 = (tid & 15) * 16;
        const int row = bx * 16 + rr;
        const int ii = item_inputs[row];
        const int qi = item_ids[row];
        const float* xs = input_embed + (size_t)ii * E_ + c0;
        const float* qs = query_embed + (size_t)qi * E_ + c0;
        float* of = outf + (size_t)row * E_ + c0;
        short* ob = outb + (size_t)row * E_ + c0;
        short* qb = qbb + (size_t)row * E_ + c0;
        #pragma unroll
        for (int q = 0; q < 4; ++q) {
            const float4 xv = reinterpret_cast<const float4*>(xs)[q];
            const float4 qv = reinterpret_cast<const float4*>(qs)[q];
            reinterpret_cast<float4*>(of)[q] = xv;
            short4 xb = { f2bf(xv.x), f2bf(xv.y), f2bf(xv.z), f2bf(xv.w) };
            short4 qb4 = { f2bf(qv.x), f2bf(qv.y), f2bf(qv.z), f2bf(qv.w) };
            reinterpret_cast<short4*>(ob)[q] = xb;
            reinterpret_cast<short4*>(qb)[q] = qb4;
        }
        return;
    }
    const int pb = bx - 512;
    if (pb < 128) {
        __shared__ short tt[64 * 72];
        const int mId = pb >> 4;
        const int l = mId >> 2, which = mId & 3;
        const float* src = (which == 0 ? Wq : which == 1 ? Wk : which == 2 ? Wv : Wo)
                         + (size_t)l * E_ * E_;
        const int tr = (pb >> 2) & 3;
        const int tc = pb & 3;
        {
            const int kl = tid >> 2;
            const int nq = (tid & 3) * 16;
            const float* sp = src + (size_t)(tr * 64 + kl) * E_ + tc * 64 + nq;
            #pragma unroll
            for (int q = 0; q < 4; ++q) {
                const float4 v = reinterpret_cast<const float4*>(sp)[q];
                tt[(nq + q * 4 + 0) * 72 + kl] = f2bf(v.x);
                tt[(nq + q * 4 + 1) * 72 + kl] = f2bf(v.y);
                tt[(nq + q * 4 + 2) * 72 + kl] = f2bf(v.z);
                tt[(nq + q * 4 + 3) * 72 + kl] = f2bf(v.w);
            }
        }
        __syncthreads();
        {
            const int nl = tid >> 2;
            const int kq = (tid & 3) * 16;
            short* dst = Wt + (size_t)mId * 65536 + (size_t)(tc * 64 + nl) * E_ + tr * 64 + kq;
            *reinterpret_cast<bf16x8*>(&dst[0]) = *reinterpret_cast<const bf16x8*>(&tt[nl * 72 + kq]);
            *reinterpret_cast<bf16x8*>(&dst[8]) = *reinterpret_cast<const bf16x8*>(&tt[nl * 72 + kq + 8]);
        }
    } else if (pb == 128) {
        const float yb = out_b[0];
        for (int i = tid; i < 8192; i += 256) y[i] = yb;
    }
}

// ---------------- QKV projection (either layer): grid (128, 4, 3)
__global__ __launch_bounds__(256) void qkv_kernel(
    const short* __restrict__ qbb, const short* __restrict__ outb,
    const short* __restrict__ Wt, const float* __restrict__ bq,
    const float* __restrict__ bk, const float* __restrict__ bv,
    short* __restrict__ Qb)
{
    __shared__ __align__(16) short As[64 * 256];
    __shared__ __align__(16) short Bs[64 * 256];
    const int bm = blockIdx.x, bn = blockIdx.y, z = blockIdx.z;
    const int tid = threadIdx.x;
    const int lane = tid & 63, w = tid >> 6;
    const int l15 = lane & 15, l4 = lane >> 4;

    const short* A = (z == 0) ? qbb : outb;
    const short* W = Wt + (size_t)z * 65536;
    const float* bias = (z == 0) ? bq : (z == 1) ? bk : bv;

    stage_tile((const char*)A + (size_t)bm * 32768, (char*)As, w, lane);
    stage_tile((const char*)W + (size_t)bn * 32768, (char*)Bs, w, lane);
    __syncthreads();

    f32x4 acc[4];
    gemm_compute(As, Bs, acc, w, l15, l4);

    short* Cz = Qb + (size_t)z * HS_;
    #pragma unroll
    for (int nf = 0; nf < 4; ++nf) {
        const int col = bn * 64 + nf * 16 + l15;
        const float bb = bias[col];
        #pragma unroll
        for (int reg = 0; reg < 4; ++reg) {
            const int rowg = bm * 64 + w * 16 + l4 * 4 + reg;
            Cz[(size_t)rowg * E_ + col] = f2bf(acc[nf][reg] + bb);
        }
    }
}

// ---------------- O-proj layer 0: grid (128, 4); outf += relu(...), outb = bf16(outf)
__global__ __launch_bounds__(256) void o0_kernel(
    const short* __restrict__ mgb, const short* __restrict__ Wo_t,
    const float* __restrict__ bo0, float* __restrict__ outf,
    short* __restrict__ outb)
{
    __shared__ __align__(16) short As[64 * 256];
    __shared__ __align__(16) short Bs[64 * 256];
    const int bm = blockIdx.x, bn = blockIdx.y;
    const int tid = threadIdx.x;
    const int lane = tid & 63, w = tid >> 6;
    const int l15 = lane & 15, l4 = lane >> 4;

    stage_tile((const char*)mgb + (size_t)bm * 32768, (char*)As, w, lane);
    stage_tile((const char*)Wo_t + (size_t)bn * 32768, (char*)Bs, w, lane);
    __syncthreads();

    f32x4 acc[4];
    gemm_compute(As, Bs, acc, w, l15, l4);

    #pragma unroll
    for (int nf = 0; nf < 4; ++nf) {
        const int col = bn * 64 + nf * 16 + l15;
        const float bb = bo0[col];
        #pragma unroll
        for (int reg = 0; reg < 4; ++reg) {
            const int rowg = bm * 64 + w * 16 + l4 * 4 + reg;
            const size_t idx = (size_t)rowg * E_ + col;
            const float o = outf[idx] + fmaxf(acc[nf][reg] + bb, 0.0f);
            outf[idx] = o;
            outb[idx] = f2bf(o);
        }
    }
}

// ---------------- paired flash attention: 256 blocks, q-tiles (7-a, a) per block
__global__ __launch_bounds__(256) void attn2_kernel(
    const short* __restrict__ Q, const short* __restrict__ K,
    const short* __restrict__ V, const float* __restrict__ pos_key,
    const float* __restrict__ pos_value, short* __restrict__ merged)
{
    __shared__ __align__(16) short Qs[64 * 72];
    __shared__ __align__(16) short Ks[64 * 64];
    __shared__ __align__(16) short Vts[4656];
    __shared__ __align__(16) short Pl[4 * 16 * 72];
    __shared__ __align__(16) short Pk[16 * 72];
    __shared__ float pv_sh[MAXPOS * 64];
    __shared__ float qpk_sh[64 * 16];
    __shared__ float pdiag[64 * 9];

    const int bid = blockIdx.x;
    const int a = bid & 3;
    const int h = (bid >> 2) & 3;
    const int b = bid >> 4;
    const int tid = threadIdx.x;
    const int lane = tid & 63;
    const int w = tid >> 6;
    const int l15 = lane & 15;
    const int l4  = lane >> 4;
    const int rloc  = l4 * 4;
    const int rbase = w * 16 + rloc;
    const int swl = (l15 & 7) << 4;

    const size_t boff = (size_t)(b * S_) * E_ + h * D_;

    for (int idx = tid; idx < MAXPOS * 64; idx += 256) pv_sh[idx] = pos_value[idx];
    for (int idx = tid; idx < 16 * 64; idx += 256) {
        const int r = idx >> 6, d = idx & 63;
        Pk[r * 72 + d] = (r < MAXPOS) ? f2bf(pos_key[r * 64 + d]) : (short)0;
    }

    for (int pass = 0; pass < 2; ++pass) {
        const int it = pass ? a : 7 - a;
        if (pass) __syncthreads();
        for (int idx = tid; idx < 64 * 9; idx += 256) pdiag[idx] = 0.0f;
        {
            const int row = tid >> 2, dq = (tid & 3) * 16;
            const short* qp = &Q[boff + (size_t)(it * 64 + row) * E_ + dq];
            *reinterpret_cast<bf16x8*>(&Qs[row * 72 + dq]) = *reinterpret_cast<const bf16x8*>(qp);
            *reinterpret_cast<bf16x8*>(&Qs[row * 72 + dq + 8]) = *reinterpret_cast<const bf16x8*>(qp + 8);
        }
        __syncthreads();

        bf16x8 aq[2];
        #pragma unroll
        for (int ks = 0; ks < 2; ++ks)
            aq[ks] = *reinterpret_cast<const bf16x8*>(&Qs[(w * 16 + l15) * 72 + ks * 32 + 8 * l4]);

        f32x4 cq = (f32x4){0.f, 0.f, 0.f, 0.f};
        #pragma unroll
        for (int ks = 0; ks < 2; ++ks) {
            const bf16x8 bpk = *reinterpret_cast<const bf16x8*>(&Pk[l15 * 72 + ks * 32 + 8 * l4]);
            cq = __builtin_amdgcn_mfma_f32_16x16x32_bf16(aq[ks], bpk, cq, 0, 0, 0);
        }
        float q9[4];
        #pragma unroll
        for (int r = 0; r < 4; ++r) {
            qpk_sh[(rbase + r) * 16 + l15] = cq[r] * 0.125f;
            q9[r] = __shfl(cq[r], l4 * 16 + 9, 64) * 0.125f;
        }

        f32x4 accv[4];
        #pragma unroll
        for (int nf = 0; nf < 4; ++nf) accv[nf] = (f32x4){0.f, 0.f, 0.f, 0.f};
        float ls[4] = {0.f, 0.f, 0.f, 0.f};

        for (int jt = 0; jt <= it; ++jt) {
            {
                const char* Kb = (const char*)(K + boff + (size_t)(jt * 64) * E_);
                #pragma unroll
                for (int c = 0; c < 2; ++c) {
                    const int chunk = w * 2 + c;
                    const int row = chunk * 8 + (lane >> 3);
                    const int col = (lane & 7) * 16;
                    const int src = row * 512 + (col ^ ((row & 7) << 4));
                    gload16(Kb + src, (char*)Ks + chunk * 1024);
                }
                const int row = tid >> 2, dq = (tid & 3) * 16;
                const short* vp = &V[boff + (size_t)(jt * 64 + row) * E_ + dq];
                const bf16x8 v0 = *reinterpret_cast<const bf16x8*>(vp);
                const bf16x8 v1 = *reinterpret_cast<const bf16x8*>(vp + 8);
                const int skew = (tid & 3) * 32 + row * 2;
                #pragma unroll
                for (int e = 0; e < 8; ++e) {
                    *(short*)((char*)Vts + (dq + e) * 144 + skew) = v0[e];
                    *(short*)((char*)Vts + (dq + 8 + e) * 144 + skew) = v1[e];
                }
            }
            __syncthreads();

            const bool near = (jt >= it - 1);
            #pragma unroll
            for (int nf = 0; nf < 4; ++nf) {
                f32x4 c = (f32x4){0.f, 0.f, 0.f, 0.f};
                const int jrow = nf * 16 + l15;
                const bf16x8 bk0 = *reinterpret_cast<const bf16x8*>(
                    (const char*)Ks + jrow * 128 + ((l4 * 16) ^ swl));
                const bf16x8 bk1 = *reinterpret_cast<const bf16x8*>(
                    (const char*)Ks + jrow * 128 + ((64 + l4 * 16) ^ swl));
                c = __builtin_amdgcn_mfma_f32_16x16x32_bf16(aq[0], bk0, c, 0, 0, 0);
                c = __builtin_amdgcn_mfma_f32_16x16x32_bf16(aq[1], bk1, c, 0, 0, 0);
                const int j = jt * 64 + nf * 16 + l15;
                #pragma unroll
                for (int r = 0; r < 4; ++r) {
                    float pp;
                    if (near) {
                        const int i = it * 64 + rbase + r;
                        const int rel = i - j;
                        if (rel < 0) pp = 0.0f;
                        else {
                            const int rc = rel < 9 ? rel : 9;
                            pp = __expf(fmaf(c[r], 0.125f, qpk_sh[(rbase + r) * 16 + rc]));
                            if (rel < 9) pdiag[(rbase + r) * 9 + rel] = pp;
                        }
                    } else {
                        pp = __expf(fmaf(c[r], 0.125f, q9[r]));
                    }
                    ls[r] += pp;
                    Pl[w * 1152 + (rloc + r) * 72 + nf * 16 + l15] = f2bf(pp);
                }
            }
            #pragma unroll
            for (int ks = 0; ks < 2; ++ks) {
                const bf16x8 pa = *reinterpret_cast<const bf16x8*>(
                    &Pl[w * 1152 + l15 * 72 + ks * 32 + 8 * l4]);
                #pragma unroll
                for (int nf = 0; nf < 4; ++nf) {
                    const int d = nf * 16 + l15;
                    const bf16x8 bv = *reinterpret_cast<const bf16x8*>(
                        (const char*)Vts + d * 144 + nf * 32 + ks * 64 + l4 * 16);
                    accv[nf] = __builtin_amdgcn_mfma_f32_16x16x32_bf16(pa, bv, accv[nf], 0, 0, 0);
                }
            }
            __syncthreads();
        }

        #pragma unroll
        for (int m = 1; m < 16; m <<= 1) {
            #pragma unroll
            for (int r = 0; r < 4; ++r) ls[r] += __shfl_xor(ls[r], m, 64);
        }

        #pragma unroll
        for (int r = 0; r < 4; ++r) {
            const int rowl = rbase + r;
            const float inv = 1.0f / ls[r];
            #pragma unroll
            for (int nf = 0; nf < 4; ++nf) {
                const int col = nf * 16 + l15;
                const float pv9 = pv_sh[9 * 64 + col];
                float extra = ls[r] * pv9;
                #pragma unroll
                for (int rr = 0; rr < 9; ++rr)
                    extra += pdiag[rowl * 9 + rr] * (pv_sh[rr * 64 + col] - pv9);
                merged[boff + (size_t)(it * 64 + rowl) * E_ + col] =
                    f2bf((accv[nf][r] + extra) * inv);
            }
        }
    }
}

// ---------------- last O-proj + final dot: grid (128, 4); y += per-block partials
__global__ __launch_bounds__(256) void o1final_kernel(
    const short* __restrict__ mgb, const short* __restrict__ Wt7,
    const float* __restrict__ bo1, const float* __restrict__ outf,
    const float* __restrict__ fw, float* __restrict__ y)
{
    __shared__ __align__(16) short As[64 * 256];
    __shared__ __align__(16) short Bs[64 * 256];
    const int bm = blockIdx.x, bn = blockIdx.y;
    const int tid = threadIdx.x;
    const int lane = tid & 63, w = tid >> 6;
    const int l15 = lane & 15, l4 = lane >> 4;

    stage_tile((const char*)mgb + (size_t)bm * 32768, (char*)As, w, lane);
    stage_tile((const char*)(Wt7 + (size_t)bn * 16384), (char*)Bs, w, lane);
    __syncthreads();

    f32x4 acc[4];
    gemm_compute(As, Bs, acc, w, l15, l4);

    float s[4] = {0.f, 0.f, 0.f, 0.f};
    #pragma unroll
    for (int nf = 0; nf < 4; ++nf) {
        const int col = bn * 64 + nf * 16 + l15;
        const float bb = bo1[col];
        const float fwv = fw[col];
        #pragma unroll
        for (int reg = 0; reg < 4; ++reg) {
            const int rowg = bm * 64 + w * 16 + l4 * 4 + reg;
            const float o = outf[(size_t)rowg * E_ + col] + fmaxf(acc[nf][reg] + bb, 0.0f);
            s[reg] += o * fwv;
        }
    }
    #pragma unroll
    for (int m = 1; m < 16; m <<= 1) {
        #pragma unroll
        for (int reg = 0; reg < 4; ++reg) s[reg] += __shfl_xor(s[reg], m, 64);
    }
    if (l15 == 0) {
        #pragma unroll
        for (int reg = 0; reg < 4; ++reg)
            atomicAdd(&y[bm * 64 + w * 16 + l4 * 4 + reg], s[reg]);
    }
}

extern "C" void kernel_launch(void* const* d_in, const int* in_sizes, int n_in,
                              void* d_out, int out_size, void* d_ws, size_t ws_size,
                              hipStream_t stream) {
    const int*   item_inputs = (const int*)d_in[0];
    const int*   item_ids    = (const int*)d_in[1];
    const float* input_embed = (const float*)d_in[2];
    const float* query_embed = (const float*)d_in[3];
    const float* pos_key     = (const float*)d_in[4];
    const float* pos_value   = (const float*)d_in[5];
    const float* Wq = (const float*)d_in[6];
    const float* bq = (const float*)d_in[7];
    const float* Wk = (const float*)d_in[8];
    const float* bk = (const float*)d_in[9];
    const float* Wv = (const float*)d_in[10];
    const float* bv = (const float*)d_in[11];
    const float* Wo = (const float*)d_in[12];
    const float* bo = (const float*)d_in[13];
    const float* out_w = (const float*)d_in[14];
    const float* out_b = (const float*)d_in[15];
    float* y = (float*)d_out;

    char* w8 = (char*)d_ws;
    float* outf = (float*)(w8);                          // 8 MB f32 hidden
    short* outb = (short*)(w8 + ((size_t)8  << 20));     // 4 MB bf16 hidden
    short* qbb  = (short*)(w8 + ((size_t)12 << 20));     // 4 MB bf16 q-base
    short* Qb   = (short*)(w8 + ((size_t)16 << 20));     // 12 MB bf16 Q,K,V
    short* mgb  = (short*)(w8 + ((size_t)28 << 20));     // 4 MB bf16 merged
    short* Wt   = (short*)(w8 + ((size_t)32 << 20));     // 1 MB bf16 weights^T

    setup_kernel<<<641, 256, 0, stream>>>(
        item_inputs, item_ids, input_embed, query_embed,
        Wq, Wk, Wv, Wo, out_b, outf, outb, qbb, Wt, y);

    // layer 0
    qkv_kernel<<<dim3(128, 4, 3), 256, 0, stream>>>(
        qbb, outb, Wt, bq, bk, bv, Qb);
    attn2_kernel<<<256, 256, 0, stream>>>(
        Qb, Qb + HS_, Qb + 2 * HS_, pos_key, pos_value, mgb);
    o0_kernel<<<dim3(128, 4), 256, 0, stream>>>(
        mgb, Wt + (size_t)3 * 65536, bo, outf, outb);

    // layer 1
    qkv_kernel<<<dim3(128, 4, 3), 256, 0, stream>>>(
        qbb, outb, Wt + (size_t)4 * 65536, bq + E_, bk + E_, bv + E_, Qb);
    attn2_kernel<<<256, 256, 0, stream>>>(
        Qb, Qb + HS_, Qb + 2 * HS_, pos_key, pos_value, mgb);
    o1final_kernel<<<dim3(128, 4), 256, 0, stream>>>(
        mgb, Wt + (size_t)7 * 65536, bo + E_, outf, out_w, y);
}

// Round 10
// 100.351 us; speedup vs baseline: 1.2813x; 1.1183x over previous
//
#include <hip/hip_runtime.h>
#include <hip/hip_bf16.h>

#define B_ 16
#define S_ 512
#define E_ 256
#define H_ 4
#define D_ 64
#define L_ 2
#define MAXPOS 10
#define HS_ ((size_t)B_ * S_ * E_)

typedef __attribute__((ext_vector_type(8))) short bf16x8;
typedef __attribute__((ext_vector_type(4))) float f32x4;

static __device__ __forceinline__ short f2bf(float f) {
    __hip_bfloat16 h = __float2bfloat16(f);
    return __builtin_bit_cast(short, h);
}

static __device__ __forceinline__ void gload16(const void* g, void* l) {
    __builtin_amdgcn_global_load_lds(
        (const __attribute__((address_space(1))) void*)(g),
        (__attribute__((address_space(3))) void*)(l),
        16, 0, 0);
}

// stage a 32 KB contiguous global tile into LDS, XOR-swizzled:
// LDS[r*512 + c] = G[r*512 + (c ^ ((r&7)<<4))]
static __device__ __forceinline__ void stage_tile(const char* gbase, char* lds,
                                                  int w, int lane) {
    #pragma unroll
    for (int c = 0; c < 8; ++c) {
        const int L = (w * 8 + c) * 1024 + lane * 16;
        const int src = L ^ (((L >> 9) & 7) << 4);
        gload16(gbase + src, lds + (w * 8 + c) * 1024);
    }
}

// 64x64 tile GEMM over K=256; named accumulator refs (rule #20).
static __device__ __forceinline__ void gemm4(const short* As, const short* Bs,
                                             int w, int l15, int l4,
                                             f32x4& a0, f32x4& a1,
                                             f32x4& a2, f32x4& a3) {
    const int sw = (l15 & 7) << 4;
    const int arow = w * 16 + l15;
    const f32x4 z4 = (f32x4){0.f, 0.f, 0.f, 0.f};
    a0 = z4; a1 = z4; a2 = z4; a3 = z4;
    #pragma unroll
    for (int ks = 0; ks < 8; ++ks) {
        const int coff = (ks * 64 + l4 * 16) ^ sw;
        const bf16x8 af = *reinterpret_cast<const bf16x8*>((const char*)As + arow * 512 + coff);
        const bf16x8 b0 = *reinterpret_cast<const bf16x8*>((const char*)Bs + (0 * 16 + l15) * 512 + coff);
        a0 = __builtin_amdgcn_mfma_f32_16x16x32_bf16(af, b0, a0, 0, 0, 0);
        const bf16x8 b1 = *reinterpret_cast<const bf16x8*>((const char*)Bs + (1 * 16 + l15) * 512 + coff);
        a1 = __builtin_amdgcn_mfma_f32_16x16x32_bf16(af, b1, a1, 0, 0, 0);
        const bf16x8 b2 = *reinterpret_cast<const bf16x8*>((const char*)Bs + (2 * 16 + l15) * 512 + coff);
        a2 = __builtin_amdgcn_mfma_f32_16x16x32_bf16(af, b2, a2, 0, 0, 0);
        const bf16x8 b3 = *reinterpret_cast<const bf16x8*>((const char*)Bs + (3 * 16 + l15) * 512 + coff);
        a3 = __builtin_amdgcn_mfma_f32_16x16x32_bf16(af, b3, a3, 0, 0, 0);
    }
}

static __device__ __forceinline__ void gemm_compute(const short* As, const short* Bs,
                                                    f32x4* acc, int w, int l15, int l4) {
    gemm4(As, Bs, w, l15, l4, acc[0], acc[1], acc[2], acc[3]);
}

// ---------------- setup: gather (16 rows/block) + Wt transpose + y init
__global__ __launch_bounds__(256) void setup_kernel(
    const int* __restrict__ item_inputs, const int* __restrict__ item_ids,
    const float* __restrict__ input_embed, const float* __restrict__ query_embed,
    const float* __restrict__ Wq, const float* __restrict__ Wk,
    const float* __restrict__ Wv, const float* __restrict__ Wo,
    const float* __restrict__ out_b,
    float* __restrict__ outf, short* __restrict__ outb, short* __restrict__ qbb,
    short* __restrict__ Wt, float* __restrict__ y)
{
    const int tid = threadIdx.x;
    const int bx = blockIdx.x;
    if (bx < 512) {
        const int rr = tid >> 4, c0 = (tid & 15) * 16;
        const int row = bx * 16 + rr;
        const int ii = item_inputs[row];
        const int qi = item_ids[row];
        const float* xs = input_embed + (size_t)ii * E_ + c0;
        const float* qs = query_embed + (size_t)qi * E_ + c0;
        float* of = outf + (size_t)row * E_ + c0;
        short* ob = outb + (size_t)row * E_ + c0;
        short* qb = qbb + (size_t)row * E_ + c0;
        #pragma unroll
        for (int q = 0; q < 4; ++q) {
            const float4 xv = reinterpret_cast<const float4*>(xs)[q];
            const float4 qv = reinterpret_cast<const float4*>(qs)[q];
            reinterpret_cast<float4*>(of)[q] = xv;
            short4 xb = { f2bf(xv.x), f2bf(xv.y), f2bf(xv.z), f2bf(xv.w) };
            short4 qb4 = { f2bf(qv.x), f2bf(qv.y), f2bf(qv.z), f2bf(qv.w) };
            reinterpret_cast<short4*>(ob)[q] = xb;
            reinterpret_cast<short4*>(qb)[q] = qb4;
        }
        return;
    }
    const int pb = bx - 512;
    if (pb < 128) {
        __shared__ short tt[64 * 72];
        const int mId = pb >> 4;
        const int l = mId >> 2, which = mId & 3;
        const float* src = (which == 0 ? Wq : which == 1 ? Wk : which == 2 ? Wv : Wo)
                         + (size_t)l * E_ * E_;
        const int tr = (pb >> 2) & 3;
        const int tc = pb & 3;
        {
            const int kl = tid >> 2;
            const int nq = (tid & 3) * 16;
            const float* sp = src + (size_t)(tr * 64 + kl) * E_ + tc * 64 + nq;
            #pragma unroll
            for (int q = 0; q < 4; ++q) {
                const float4 v = reinterpret_cast<const float4*>(sp)[q];
                tt[(nq + q * 4 + 0) * 72 + kl] = f2bf(v.x);
                tt[(nq + q * 4 + 1) * 72 + kl] = f2bf(v.y);
                tt[(nq + q * 4 + 2) * 72 + kl] = f2bf(v.z);
                tt[(nq + q * 4 + 3) * 72 + kl] = f2bf(v.w);
            }
        }
        __syncthreads();
        {
            const int nl = tid >> 2;
            const int kq = (tid & 3) * 16;
            short* dst = Wt + (size_t)mId * 65536 + (size_t)(tc * 64 + nl) * E_ + tr * 64 + kq;
            *reinterpret_cast<bf16x8*>(&dst[0]) = *reinterpret_cast<const bf16x8*>(&tt[nl * 72 + kq]);
            *reinterpret_cast<bf16x8*>(&dst[8]) = *reinterpret_cast<const bf16x8*>(&tt[nl * 72 + kq + 8]);
        }
    } else if (pb == 128) {
        const float yb = out_b[0];
        for (int i = tid; i < 8192; i += 256) y[i] = yb;
    }
}

// ---------------- layer-0 QKV + layer-1 Q: grid (128, 4, 4)
__global__ __launch_bounds__(256) void qkv0_kernel(
    const short* __restrict__ qbb, const short* __restrict__ outb,
    const short* __restrict__ Wt, const float* __restrict__ bq,
    const float* __restrict__ bk, const float* __restrict__ bv,
    const float* __restrict__ bq1, short* __restrict__ Qb,
    short* __restrict__ Qb1)
{
    __shared__ __align__(16) short As[64 * 256];
    __shared__ __align__(16) short Bs[64 * 256];
    const int bm = blockIdx.x, bn = blockIdx.y, z = blockIdx.z;
    const int tid = threadIdx.x;
    const int lane = tid & 63, w = tid >> 6;
    const int l15 = lane & 15, l4 = lane >> 4;

    const short* A = (z == 1 || z == 2) ? outb : qbb;
    const short* W = (z == 3) ? (Wt + (size_t)4 * 65536) : (Wt + (size_t)z * 65536);
    const float* bias = (z == 0) ? bq : (z == 1) ? bk : (z == 2) ? bv : bq1;

    stage_tile((const char*)A + (size_t)bm * 32768, (char*)As, w, lane);
    stage_tile((const char*)W + (size_t)bn * 32768, (char*)Bs, w, lane);
    __syncthreads();

    f32x4 acc[4];
    gemm_compute(As, Bs, acc, w, l15, l4);

    short* Cz = (z == 3) ? Qb1 : Qb + (size_t)z * HS_;
    #pragma unroll
    for (int nf = 0; nf < 4; ++nf) {
        const int col = bn * 64 + nf * 16 + l15;
        const float bb = bias[col];
        #pragma unroll
        for (int reg = 0; reg < 4; ++reg) {
            const int rowg = bm * 64 + w * 16 + l4 * 4 + reg;
            Cz[(size_t)rowg * E_ + col] = f2bf(acc[nf][reg] + bb);
        }
    }
}

// ---------------- layer-1 K,V: grid (128, 4, 2)
__global__ __launch_bounds__(256) void kv1_kernel(
    const short* __restrict__ outb, const short* __restrict__ Wt1,
    const float* __restrict__ bk1, const float* __restrict__ bv1,
    short* __restrict__ Qb)
{
    __shared__ __align__(16) short As[64 * 256];
    __shared__ __align__(16) short Bs[64 * 256];
    const int bm = blockIdx.x, bn = blockIdx.y, z = blockIdx.z;
    const int tid = threadIdx.x;
    const int lane = tid & 63, w = tid >> 6;
    const int l15 = lane & 15, l4 = lane >> 4;

    const short* W = Wt1 + (size_t)(z + 1) * 65536;   // Wk1 / Wv1
    const float* bias = (z == 0) ? bk1 : bv1;

    stage_tile((const char*)outb + (size_t)bm * 32768, (char*)As, w, lane);
    stage_tile((const char*)W + (size_t)bn * 32768, (char*)Bs, w, lane);
    __syncthreads();

    f32x4 acc[4];
    gemm_compute(As, Bs, acc, w, l15, l4);

    short* Cz = Qb + (size_t)(z + 1) * HS_;
    #pragma unroll
    for (int nf = 0; nf < 4; ++nf) {
        const int col = bn * 64 + nf * 16 + l15;
        const float bb = bias[col];
        #pragma unroll
        for (int reg = 0; reg < 4; ++reg) {
            const int rowg = bm * 64 + w * 16 + l4 * 4 + reg;
            Cz[(size_t)rowg * E_ + col] = f2bf(acc[nf][reg] + bb);
        }
    }
}

// ---------------- O-proj layer 0: grid (128, 4)
__global__ __launch_bounds__(256) void o0_kernel(
    const short* __restrict__ mgb, const short* __restrict__ Wo_t,
    const float* __restrict__ bo0, float* __restrict__ outf,
    short* __restrict__ outb)
{
    __shared__ __align__(16) short As[64 * 256];
    __shared__ __align__(16) short Bs[64 * 256];
    const int bm = blockIdx.x, bn = blockIdx.y;
    const int tid = threadIdx.x;
    const int lane = tid & 63, w = tid >> 6;
    const int l15 = lane & 15, l4 = lane >> 4;

    stage_tile((const char*)mgb + (size_t)bm * 32768, (char*)As, w, lane);
    stage_tile((const char*)Wo_t + (size_t)bn * 32768, (char*)Bs, w, lane);
    __syncthreads();

    f32x4 acc[4];
    gemm_compute(As, Bs, acc, w, l15, l4);

    #pragma unroll
    for (int nf = 0; nf < 4; ++nf) {
        const int col = bn * 64 + nf * 16 + l15;
        const float bb = bo0[col];
        #pragma unroll
        for (int reg = 0; reg < 4; ++reg) {
            const int rowg = bm * 64 + w * 16 + l4 * 4 + reg;
            const size_t idx = (size_t)rowg * E_ + col;
            const float o = outf[idx] + fmaxf(acc[nf][reg] + bb, 0.0f);
            outf[idx] = o;
            outb[idx] = f2bf(o);
        }
    }
}

// ---------------- flash attention: 512 blocks, double-buffered K/V, 1 barrier/iter
__global__ __launch_bounds__(256) void attn_kernel(
    const short* __restrict__ Q, const short* __restrict__ K,
    const short* __restrict__ V, const float* __restrict__ pos_key,
    const float* __restrict__ pos_value, short* __restrict__ merged)
{
    __shared__ __align__(16) short Qs[64 * 72];
    __shared__ __align__(16) short Ks[2][64 * 64];
    __shared__ __align__(16) short Vts[2][4656];
    __shared__ __align__(16) short Pl[4 * 16 * 72];
    __shared__ __align__(16) short Pk[16 * 72];
    __shared__ float pv_sh[MAXPOS * 64];
    __shared__ float qpk_sh[64 * 16];
    __shared__ float pdiag[64 * 9];

    const int bid = blockIdx.x;
    const int it = 7 - (bid & 7);
    const int h  = (bid >> 3) & 3;
    const int b  = bid >> 5;
    const int tid = threadIdx.x;
    const int lane = tid & 63;
    const int w = tid >> 6;
    const int l15 = lane & 15;
    const int l4  = lane >> 4;
    const int rloc  = l4 * 4;
    const int rbase = w * 16 + rloc;
    const int swl = (l15 & 7) << 4;
    const float SC = 0.18033688f;   // 0.125 * log2(e)

    const size_t boff = (size_t)(b * S_) * E_ + h * D_;

    for (int idx = tid; idx < MAXPOS * 64; idx += 256) pv_sh[idx] = pos_value[idx];
    for (int idx = tid; idx < 64 * 9; idx += 256) pdiag[idx] = 0.0f;
    for (int idx = tid; idx < 16 * 64; idx += 256) {
        const int r = idx >> 6, d = idx & 63;
        Pk[r * 72 + d] = (r < MAXPOS) ? f2bf(pos_key[r * 64 + d]) : (short)0;
    }
    {
        const int row = tid >> 2, dq = (tid & 3) * 16;
        const short* qp = &Q[boff + (size_t)(it * 64 + row) * E_ + dq];
        *reinterpret_cast<bf16x8*>(&Qs[row * 72 + dq]) = *reinterpret_cast<const bf16x8*>(qp);
        *reinterpret_cast<bf16x8*>(&Qs[row * 72 + dq + 8]) = *reinterpret_cast<const bf16x8*>(qp + 8);
    }

    auto stageKV = [&](int jt, int buf) {
        const char* Kb = (const char*)(K + boff + (size_t)(jt * 64) * E_);
        #pragma unroll
        for (int c = 0; c < 2; ++c) {
            const int chunk = w * 2 + c;
            const int row = chunk * 8 + (lane >> 3);
            const int col = (lane & 7) * 16;
            const int src = row * 512 + (col ^ ((row & 7) << 4));
            gload16(Kb + src, (char*)Ks[buf] + chunk * 1024);
        }
        const int row = tid >> 2, dq = (tid & 3) * 16;
        const short* vp = &V[boff + (size_t)(jt * 64 + row) * E_ + dq];
        const bf16x8 v0 = *reinterpret_cast<const bf16x8*>(vp);
        const bf16x8 v1 = *reinterpret_cast<const bf16x8*>(vp + 8);
        const int skew = (tid & 3) * 32 + row * 2;
        #pragma unroll
        for (int e = 0; e < 8; ++e) {
            *(short*)((char*)Vts[buf] + (dq + e) * 144 + skew) = v0[e];
            *(short*)((char*)Vts[buf] + (dq + 8 + e) * 144 + skew) = v1[e];
        }
    };

    stageKV(0, 0);
    __syncthreads();

    bf16x8 aq[2];
    #pragma unroll
    for (int ks = 0; ks < 2; ++ks)
        aq[ks] = *reinterpret_cast<const bf16x8*>(&Qs[(w * 16 + l15) * 72 + ks * 32 + 8 * l4]);

    f32x4 cq = (f32x4){0.f, 0.f, 0.f, 0.f};
    #pragma unroll
    for (int ks = 0; ks < 2; ++ks) {
        const bf16x8 bpk = *reinterpret_cast<const bf16x8*>(&Pk[l15 * 72 + ks * 32 + 8 * l4]);
        cq = __builtin_amdgcn_mfma_f32_16x16x32_bf16(aq[ks], bpk, cq, 0, 0, 0);
    }
    float q9[4];
    #pragma unroll
    for (int r = 0; r < 4; ++r) {
        qpk_sh[(rbase + r) * 16 + l15] = cq[r] * SC;
        q9[r] = __shfl(cq[r], l4 * 16 + 9, 64) * SC;
    }

    f32x4 accv[4];
    #pragma unroll
    for (int nf = 0; nf < 4; ++nf) accv[nf] = (f32x4){0.f, 0.f, 0.f, 0.f};
    float ls[4] = {0.f, 0.f, 0.f, 0.f};

    for (int jt = 0; jt <= it; ++jt) {
        const int cur = jt & 1;
        if (jt < it) stageKV(jt + 1, cur ^ 1);

        const bool near = (jt >= it - 1);
        #pragma unroll
        for (int nf = 0; nf < 4; ++nf) {
            f32x4 c = (f32x4){0.f, 0.f, 0.f, 0.f};
            const int jrow = nf * 16 + l15;
            const bf16x8 bk0 = *reinterpret_cast<const bf16x8*>(
                (const char*)Ks[cur] + jrow * 128 + ((l4 * 16) ^ swl));
            const bf16x8 bk1 = *reinterpret_cast<const bf16x8*>(
                (const char*)Ks[cur] + jrow * 128 + ((64 + l4 * 16) ^ swl));
            c = __builtin_amdgcn_mfma_f32_16x16x32_bf16(aq[0], bk0, c, 0, 0, 0);
            c = __builtin_amdgcn_mfma_f32_16x16x32_bf16(aq[1], bk1, c, 0, 0, 0);
            const int j = jt * 64 + nf * 16 + l15;
            #pragma unroll
            for (int r = 0; r < 4; ++r) {
                float pp;
                if (near) {
                    const int i = it * 64 + rbase + r;
                    const int rel = i - j;
                    if (rel < 0) pp = 0.0f;
                    else {
                        const int rc = rel < 9 ? rel : 9;
                        pp = exp2f(fmaf(c[r], SC, qpk_sh[(rbase + r) * 16 + rc]));
                        if (rel < 9) pdiag[(rbase + r) * 9 + rel] = pp;
                    }
                } else {
                    pp = exp2f(fmaf(c[r], SC, q9[r]));
                }
                ls[r] += pp;
                Pl[w * 1152 + (rloc + r) * 72 + nf * 16 + l15] = f2bf(pp);
            }
        }
        #pragma unroll
        for (int ks = 0; ks < 2; ++ks) {
            const bf16x8 pa = *reinterpret_cast<const bf16x8*>(
                &Pl[w * 1152 + l15 * 72 + ks * 32 + 8 * l4]);
            #pragma unroll
            for (int nf = 0; nf < 4; ++nf) {
                const int d = nf * 16 + l15;
                const bf16x8 bv = *reinterpret_cast<const bf16x8*>(
                    (const char*)Vts[cur] + d * 144 + nf * 32 + ks * 64 + l4 * 16);
                accv[nf] = __builtin_amdgcn_mfma_f32_16x16x32_bf16(pa, bv, accv[nf], 0, 0, 0);
            }
        }
        __syncthreads();
    }

    #pragma unroll
    for (int m = 1; m < 16; m <<= 1) {
        #pragma unroll
        for (int r = 0; r < 4; ++r) ls[r] += __shfl_xor(ls[r], m, 64);
    }

    #pragma unroll
    for (int r = 0; r < 4; ++r) {
        const int rowl = rbase + r;
        const float inv = 1.0f / ls[r];
        #pragma unroll
        for (int nf = 0; nf < 4; ++nf) {
            const int col = nf * 16 + l15;
            const float pv9 = pv_sh[9 * 64 + col];
            float extra = ls[r] * pv9;
            #pragma unroll
            for (int rr = 0; rr < 9; ++rr)
                extra += pdiag[rowl * 9 + rr] * (pv_sh[rr * 64 + col] - pv9);
            merged[boff + (size_t)(it * 64 + rowl) * E_ + col] =
                f2bf((accv[nf][r] + extra) * inv);
        }
    }
}

// ---------------- last O-proj + final dot: grid (128, 4)
__global__ __launch_bounds__(256) void o1final_kernel(
    const short* __restrict__ mgb, const short* __restrict__ Wt7,
    const float* __restrict__ bo1, const float* __restrict__ outf,
    const float* __restrict__ fw, float* __restrict__ y)
{
    __shared__ __align__(16) short As[64 * 256];
    __shared__ __align__(16) short Bs[64 * 256];
    const int bm = blockIdx.x, bn = blockIdx.y;
    const int tid = threadIdx.x;
    const int lane = tid & 63, w = tid >> 6;
    const int l15 = lane & 15, l4 = lane >> 4;

    stage_tile((const char*)mgb + (size_t)bm * 32768, (char*)As, w, lane);
    stage_tile((const char*)Wt7 + (size_t)bn * 32768, (char*)Bs, w, lane);
    __syncthreads();

    f32x4 acc[4];
    gemm_compute(As, Bs, acc, w, l15, l4);

    float s[4] = {0.f, 0.f, 0.f, 0.f};
    #pragma unroll
    for (int nf = 0; nf < 4; ++nf) {
        const int col = bn * 64 + nf * 16 + l15;
        const float bb = bo1[col];
        const float fwv = fw[col];
        #pragma unroll
        for (int reg = 0; reg < 4; ++reg) {
            const int rowg = bm * 64 + w * 16 + l4 * 4 + reg;
            const float o = outf[(size_t)rowg * E_ + col] + fmaxf(acc[nf][reg] + bb, 0.0f);
            s[reg] += o * fwv;
        }
    }
    #pragma unroll
    for (int m = 1; m < 16; m <<= 1) {
        #pragma unroll
        for (int reg = 0; reg < 4; ++reg) s[reg] += __shfl_xor(s[reg], m, 64);
    }
    if (l15 == 0) {
        #pragma unroll
        for (int reg = 0; reg < 4; ++reg)
            atomicAdd(&y[bm * 64 + w * 16 + l4 * 4 + reg], s[reg]);
    }
}

extern "C" void kernel_launch(void* const* d_in, const int* in_sizes, int n_in,
                              void* d_out, int out_size, void* d_ws, size_t ws_size,
                              hipStream_t stream) {
    const int*   item_inputs = (const int*)d_in[0];
    const int*   item_ids    = (const int*)d_in[1];
    const float* input_embed = (const float*)d_in[2];
    const float* query_embed = (const float*)d_in[3];
    const float* pos_key     = (const float*)d_in[4];
    const float* pos_value   = (const float*)d_in[5];
    const float* Wq = (const float*)d_in[6];
    const float* bq = (const float*)d_in[7];
    const float* Wk = (const float*)d_in[8];
    const float* bk = (const float*)d_in[9];
    const float* Wv = (const float*)d_in[10];
    const float* bv = (const float*)d_in[11];
    const float* Wo = (const float*)d_in[12];
    const float* bo = (const float*)d_in[13];
    const float* out_w = (const float*)d_in[14];
    const float* out_b = (const float*)d_in[15];
    float* y = (float*)d_out;

    char* w8 = (char*)d_ws;
    float* outf = (float*)(w8);                          // 8 MB f32 hidden
    short* outb = (short*)(w8 + ((size_t)8  << 20));     // 4 MB bf16 hidden
    short* qbb  = (short*)(w8 + ((size_t)12 << 20));     // 4 MB bf16 q-base
    short* Qb   = (short*)(w8 + ((size_t)16 << 20));     // 12 MB bf16 Q,K,V
    short* mgb  = (short*)(w8 + ((size_t)28 << 20));     // 4 MB bf16 merged
    short* Wt   = (short*)(w8 + ((size_t)32 << 20));     // 1 MB bf16 weights^T
    short* Qb1  = (short*)(w8 + ((size_t)34 << 20));     // 4 MB bf16 Q (layer 1)

    setup_kernel<<<641, 256, 0, stream>>>(
        item_inputs, item_ids, input_embed, query_embed,
        Wq, Wk, Wv, Wo, out_b, outf, outb, qbb, Wt, y);

    qkv0_kernel<<<dim3(128, 4, 4), 256, 0, stream>>>(
        qbb, outb, Wt, bq, bk, bv, bq + E_, Qb, Qb1);
    attn_kernel<<<512, 256, 0, stream>>>(
        Qb, Qb + HS_, Qb + 2 * HS_, pos_key, pos_value, mgb);
    o0_kernel<<<dim3(128, 4), 256, 0, stream>>>(
        mgb, Wt + (size_t)3 * 65536, bo, outf, outb);

    kv1_kernel<<<dim3(128, 4, 2), 256, 0, stream>>>(
        outb, Wt + (size_t)4 * 65536, bk + E_, bv + E_, Qb);
    attn_kernel<<<512, 256, 0, stream>>>(
        Qb1, Qb + HS_, Qb + 2 * HS_, pos_key, pos_value, mgb);
    o1final_kernel<<<dim3(128, 4), 256, 0, stream>>>(
        mgb, Wt + (size_t)7 * 65536, bo + E_, outf, out_w, y);
}

// Round 11
// 90.565 us; speedup vs baseline: 1.4198x; 1.1081x over previous
//
#include <hip/hip_runtime.h>
#include <hip/hip_bf16.h>

#define B_ 16
#define S_ 512
#define E_ 256
#define H_ 4
#define D_ 64
#define L_ 2
#define MAXPOS 10
#define HS_ ((size_t)B_ * S_ * E_)

typedef __attribute__((ext_vector_type(8))) short bf16x8;
typedef __attribute__((ext_vector_type(4))) float f32x4;

static __device__ __forceinline__ short f2bf(float f) {
    __hip_bfloat16 h = __float2bfloat16(f);
    return __builtin_bit_cast(short, h);
}

static __device__ __forceinline__ void gload16(const void* g, void* l) {
    __builtin_amdgcn_global_load_lds(
        (const __attribute__((address_space(1))) void*)(g),
        (__attribute__((address_space(3))) void*)(l),
        16, 0, 0);
}

// stage a 32 KB contiguous global tile into LDS, XOR-swizzled:
// LDS[r*512 + c] = G[r*512 + (c ^ ((r&7)<<4))]
static __device__ __forceinline__ void stage_tile(const char* gbase, char* lds,
                                                  int w, int lane) {
    #pragma unroll
    for (int c = 0; c < 8; ++c) {
        const int L = (w * 8 + c) * 1024 + lane * 16;
        const int src = L ^ (((L >> 9) & 7) << 4);
        gload16(gbase + src, lds + (w * 8 + c) * 1024);
    }
}

// 64x64 tile GEMM over K=256; named accumulator refs (rule #20).
static __device__ __forceinline__ void gemm4(const short* As, const short* Bs,
                                             int w, int l15, int l4,
                                             f32x4& a0, f32x4& a1,
                                             f32x4& a2, f32x4& a3) {
    const int sw = (l15 & 7) << 4;
    const int arow = w * 16 + l15;
    const f32x4 z4 = (f32x4){0.f, 0.f, 0.f, 0.f};
    a0 = z4; a1 = z4; a2 = z4; a3 = z4;
    #pragma unroll
    for (int ks = 0; ks < 8; ++ks) {
        const int coff = (ks * 64 + l4 * 16) ^ sw;
        const bf16x8 af = *reinterpret_cast<const bf16x8*>((const char*)As + arow * 512 + coff);
        const bf16x8 b0 = *reinterpret_cast<const bf16x8*>((const char*)Bs + (0 * 16 + l15) * 512 + coff);
        a0 = __builtin_amdgcn_mfma_f32_16x16x32_bf16(af, b0, a0, 0, 0, 0);
        const bf16x8 b1 = *reinterpret_cast<const bf16x8*>((const char*)Bs + (1 * 16 + l15) * 512 + coff);
        a1 = __builtin_amdgcn_mfma_f32_16x16x32_bf16(af, b1, a1, 0, 0, 0);
        const bf16x8 b2 = *reinterpret_cast<const bf16x8*>((const char*)Bs + (2 * 16 + l15) * 512 + coff);
        a2 = __builtin_amdgcn_mfma_f32_16x16x32_bf16(af, b2, a2, 0, 0, 0);
        const bf16x8 b3 = *reinterpret_cast<const bf16x8*>((const char*)Bs + (3 * 16 + l15) * 512 + coff);
        a3 = __builtin_amdgcn_mfma_f32_16x16x32_bf16(af, b3, a3, 0, 0, 0);
    }
}

static __device__ __forceinline__ void gemm_compute(const short* As, const short* Bs,
                                                    f32x4* acc, int w, int l15, int l4) {
    gemm4(As, Bs, w, l15, l4, acc[0], acc[1], acc[2], acc[3]);
}

// ---------------- setup: gather bf16 (16 rows/block) + Wt transpose + y init
__global__ __launch_bounds__(256) void setup_kernel(
    const int* __restrict__ item_inputs, const int* __restrict__ item_ids,
    const float* __restrict__ input_embed, const float* __restrict__ query_embed,
    const float* __restrict__ Wq, const float* __restrict__ Wk,
    const float* __restrict__ Wv, const float* __restrict__ Wo,
    const float* __restrict__ out_b,
    short* __restrict__ outb, short* __restrict__ qbb,
    short* __restrict__ Wt, float* __restrict__ y)
{
    const int tid = threadIdx.x;
    const int bx = blockIdx.x;
    if (bx < 512) {
        const int rr = tid >> 4, c0 = (tid & 15) * 16;
        const int row = bx * 16 + rr;
        const int ii = item_inputs[row];
        const int qi = item_ids[row];
        const float* xs = input_embed + (size_t)ii * E_ + c0;
        const float* qs = query_embed + (size_t)qi * E_ + c0;
        short* ob = outb + (size_t)row * E_ + c0;
        short* qb = qbb + (size_t)row * E_ + c0;
        #pragma unroll
        for (int q = 0; q < 4; ++q) {
            const float4 xv = reinterpret_cast<const float4*>(xs)[q];
            const float4 qv = reinterpret_cast<const float4*>(qs)[q];
            short4 xb = { f2bf(xv.x), f2bf(xv.y), f2bf(xv.z), f2bf(xv.w) };
            short4 qb4 = { f2bf(qv.x), f2bf(qv.y), f2bf(qv.z), f2bf(qv.w) };
            reinterpret_cast<short4*>(ob)[q] = xb;
            reinterpret_cast<short4*>(qb)[q] = qb4;
        }
        return;
    }
    const int pb = bx - 512;
    if (pb < 128) {
        __shared__ short tt[64 * 72];
        const int mId = pb >> 4;
        const int l = mId >> 2, which = mId & 3;
        const float* src = (which == 0 ? Wq : which == 1 ? Wk : which == 2 ? Wv : Wo)
                         + (size_t)l * E_ * E_;
        const int tr = (pb >> 2) & 3;
        const int tc = pb & 3;
        {
            const int kl = tid >> 2;
            const int nq = (tid & 3) * 16;
            const float* sp = src + (size_t)(tr * 64 + kl) * E_ + tc * 64 + nq;
            #pragma unroll
            for (int q = 0; q < 4; ++q) {
                const float4 v = reinterpret_cast<const float4*>(sp)[q];
                tt[(nq + q * 4 + 0) * 72 + kl] = f2bf(v.x);
                tt[(nq + q * 4 + 1) * 72 + kl] = f2bf(v.y);
                tt[(nq + q * 4 + 2) * 72 + kl] = f2bf(v.z);
                tt[(nq + q * 4 + 3) * 72 + kl] = f2bf(v.w);
            }
        }
        __syncthreads();
        {
            const int nl = tid >> 2;
            const int kq = (tid & 3) * 16;
            short* dst = Wt + (size_t)mId * 65536 + (size_t)(tc * 64 + nl) * E_ + tr * 64 + kq;
            *reinterpret_cast<bf16x8*>(&dst[0]) = *reinterpret_cast<const bf16x8*>(&tt[nl * 72 + kq]);
            *reinterpret_cast<bf16x8*>(&dst[8]) = *reinterpret_cast<const bf16x8*>(&tt[nl * 72 + kq + 8]);
        }
    } else if (pb == 128) {
        const float yb = out_b[0];
        for (int i = tid; i < 8192; i += 256) y[i] = yb;
    }
}

// ---------------- layer-0 QKV + layer-1 Q: grid (128, 4, 4)
__global__ __launch_bounds__(256) void qkv0_kernel(
    const short* __restrict__ qbb, const short* __restrict__ outb,
    const short* __restrict__ Wt, const float* __restrict__ bq,
    const float* __restrict__ bk, const float* __restrict__ bv,
    const float* __restrict__ bq1, short* __restrict__ Qb,
    short* __restrict__ Qb1)
{
    __shared__ __align__(16) short As[64 * 256];
    __shared__ __align__(16) short Bs[64 * 256];
    const int bm = blockIdx.x, bn = blockIdx.y, z = blockIdx.z;
    const int tid = threadIdx.x;
    const int lane = tid & 63, w = tid >> 6;
    const int l15 = lane & 15, l4 = lane >> 4;

    const short* A = (z == 1 || z == 2) ? outb : qbb;
    const short* W = (z == 3) ? (Wt + (size_t)4 * 65536) : (Wt + (size_t)z * 65536);
    const float* bias = (z == 0) ? bq : (z == 1) ? bk : (z == 2) ? bv : bq1;

    stage_tile((const char*)A + (size_t)bm * 32768, (char*)As, w, lane);
    stage_tile((const char*)W + (size_t)bn * 32768, (char*)Bs, w, lane);
    __syncthreads();

    f32x4 acc[4];
    gemm_compute(As, Bs, acc, w, l15, l4);

    short* Cz = (z == 3) ? Qb1 : Qb + (size_t)z * HS_;
    #pragma unroll
    for (int nf = 0; nf < 4; ++nf) {
        const int col = bn * 64 + nf * 16 + l15;
        const float bb = bias[col];
        #pragma unroll
        for (int reg = 0; reg < 4; ++reg) {
            const int rowg = bm * 64 + w * 16 + l4 * 4 + reg;
            Cz[(size_t)rowg * E_ + col] = f2bf(acc[nf][reg] + bb);
        }
    }
}

// ---------------- layer-1 K,V: grid (128, 4, 2)
__global__ __launch_bounds__(256) void kv1_kernel(
    const short* __restrict__ outb, const short* __restrict__ Wt1,
    const float* __restrict__ bk1, const float* __restrict__ bv1,
    short* __restrict__ Qb)
{
    __shared__ __align__(16) short As[64 * 256];
    __shared__ __align__(16) short Bs[64 * 256];
    const int bm = blockIdx.x, bn = blockIdx.y, z = blockIdx.z;
    const int tid = threadIdx.x;
    const int lane = tid & 63, w = tid >> 6;
    const int l15 = lane & 15, l4 = lane >> 4;

    const short* W = Wt1 + (size_t)(z + 1) * 65536;   // Wk1 / Wv1
    const float* bias = (z == 0) ? bk1 : bv1;

    stage_tile((const char*)outb + (size_t)bm * 32768, (char*)As, w, lane);
    stage_tile((const char*)W + (size_t)bn * 32768, (char*)Bs, w, lane);
    __syncthreads();

    f32x4 acc[4];
    gemm_compute(As, Bs, acc, w, l15, l4);

    short* Cz = Qb + (size_t)(z + 1) * HS_;
    #pragma unroll
    for (int nf = 0; nf < 4; ++nf) {
        const int col = bn * 64 + nf * 16 + l15;
        const float bb = bias[col];
        #pragma unroll
        for (int reg = 0; reg < 4; ++reg) {
            const int rowg = bm * 64 + w * 16 + l4 * 4 + reg;
            Cz[(size_t)rowg * E_ + col] = f2bf(acc[nf][reg] + bb);
        }
    }
}

// ---------------- O-proj layer 0: grid (128, 4)
// residual gathered directly from input_embed (outf first written here)
__global__ __launch_bounds__(256) void o0_kernel(
    const short* __restrict__ mgb, const short* __restrict__ Wo_t,
    const float* __restrict__ bo0, const int* __restrict__ item_inputs,
    const float* __restrict__ input_embed, float* __restrict__ outf,
    short* __restrict__ outb)
{
    __shared__ __align__(16) short As[64 * 256];
    __shared__ __align__(16) short Bs[64 * 256];
    const int bm = blockIdx.x, bn = blockIdx.y;
    const int tid = threadIdx.x;
    const int lane = tid & 63, w = tid >> 6;
    const int l15 = lane & 15, l4 = lane >> 4;

    stage_tile((const char*)mgb + (size_t)bm * 32768, (char*)As, w, lane);
    stage_tile((const char*)Wo_t + (size_t)bn * 32768, (char*)Bs, w, lane);
    __syncthreads();

    f32x4 acc[4];
    gemm_compute(As, Bs, acc, w, l15, l4);

    #pragma unroll
    for (int reg = 0; reg < 4; ++reg) {
        const int rowg = bm * 64 + w * 16 + l4 * 4 + reg;
        const int ii = item_inputs[rowg];
        const float* emb = input_embed + (size_t)ii * E_;
        #pragma unroll
        for (int nf = 0; nf < 4; ++nf) {
            const int col = bn * 64 + nf * 16 + l15;
            const size_t idx = (size_t)rowg * E_ + col;
            const float o = emb[col] + fmaxf(acc[nf][reg] + bo0[col], 0.0f);
            outf[idx] = o;
            outb[idx] = f2bf(o);
        }
    }
}

// ---------------- flash attention: 512 blocks, double-buffered K/V.
// Complementary-it pairing: bid p and p+256 (same CU under mod-8 XCD
// round-robin) get its {7-tp, tp} -> every CU runs exactly 9 j-iterations.
__global__ __launch_bounds__(256) void attn_kernel(
    const short* __restrict__ Q, const short* __restrict__ K,
    const short* __restrict__ V, const float* __restrict__ pos_key,
    const float* __restrict__ pos_value, short* __restrict__ merged)
{
    __shared__ __align__(16) short Qs[64 * 72];
    __shared__ __align__(16) short Ks[2][64 * 64];
    __shared__ __align__(16) short Vts[2][4656];
    __shared__ __align__(16) short Pl[4 * 16 * 72];
    __shared__ __align__(16) short Pk[16 * 72];
    __shared__ float pv_sh[MAXPOS * 64];
    __shared__ float qpk_sh[64 * 16];
    __shared__ float pdiag[64 * 9];

    const int bid = blockIdx.x;
    const int half = bid >> 8;          // 0: its {7..4}, 1: its {0..3}
    const int g = bid & 255;
    const int tp = g & 3;
    const int bh = g >> 2;              // 0..63
    const int it = half ? tp : 7 - tp;
    const int h = bh & 3;
    const int b = bh >> 2;
    const int tid = threadIdx.x;
    const int lane = tid & 63;
    const int w = tid >> 6;
    const int l15 = lane & 15;
    const int l4  = lane >> 4;
    const int rloc  = l4 * 4;
    const int rbase = w * 16 + rloc;
    const int swl = (l15 & 7) << 4;
    const float SC = 0.18033688f;   // 0.125 * log2(e)

    const size_t boff = (size_t)(b * S_) * E_ + h * D_;

    for (int idx = tid; idx < MAXPOS * 64; idx += 256) pv_sh[idx] = pos_value[idx];
    for (int idx = tid; idx < 64 * 9; idx += 256) pdiag[idx] = 0.0f;
    for (int idx = tid; idx < 16 * 64; idx += 256) {
        const int r = idx >> 6, d = idx & 63;
        Pk[r * 72 + d] = (r < MAXPOS) ? f2bf(pos_key[r * 64 + d]) : (short)0;
    }
    {
        const int row = tid >> 2, dq = (tid & 3) * 16;
        const short* qp = &Q[boff + (size_t)(it * 64 + row) * E_ + dq];
        *reinterpret_cast<bf16x8*>(&Qs[row * 72 + dq]) = *reinterpret_cast<const bf16x8*>(qp);
        *reinterpret_cast<bf16x8*>(&Qs[row * 72 + dq + 8]) = *reinterpret_cast<const bf16x8*>(qp + 8);
    }

    auto stageKV = [&](int jt, int buf) {
        const char* Kb = (const char*)(K + boff + (size_t)(jt * 64) * E_);
        #pragma unroll
        for (int c = 0; c < 2; ++c) {
            const int chunk = w * 2 + c;
            const int row = chunk * 8 + (lane >> 3);
            const int col = (lane & 7) * 16;
            const int src = row * 512 + (col ^ ((row & 7) << 4));
            gload16(Kb + src, (char*)Ks[buf] + chunk * 1024);
        }
        const int row = tid >> 2, dq = (tid & 3) * 16;
        const short* vp = &V[boff + (size_t)(jt * 64 + row) * E_ + dq];
        const bf16x8 v0 = *reinterpret_cast<const bf16x8*>(vp);
        const bf16x8 v1 = *reinterpret_cast<const bf16x8*>(vp + 8);
        const int skew = (tid & 3) * 32 + row * 2;
        #pragma unroll
        for (int e = 0; e < 8; ++e) {
            *(short*)((char*)Vts[buf] + (dq + e) * 144 + skew) = v0[e];
            *(short*)((char*)Vts[buf] + (dq + 8 + e) * 144 + skew) = v1[e];
        }
    };

    stageKV(0, 0);
    __syncthreads();

    bf16x8 aq[2];
    #pragma unroll
    for (int ks = 0; ks < 2; ++ks)
        aq[ks] = *reinterpret_cast<const bf16x8*>(&Qs[(w * 16 + l15) * 72 + ks * 32 + 8 * l4]);

    f32x4 cq = (f32x4){0.f, 0.f, 0.f, 0.f};
    #pragma unroll
    for (int ks = 0; ks < 2; ++ks) {
        const bf16x8 bpk = *reinterpret_cast<const bf16x8*>(&Pk[l15 * 72 + ks * 32 + 8 * l4]);
        cq = __builtin_amdgcn_mfma_f32_16x16x32_bf16(aq[ks], bpk, cq, 0, 0, 0);
    }
    float q9[4];
    #pragma unroll
    for (int r = 0; r < 4; ++r) {
        qpk_sh[(rbase + r) * 16 + l15] = cq[r] * SC;
        q9[r] = __shfl(cq[r], l4 * 16 + 9, 64) * SC;
    }

    f32x4 accv[4];
    #pragma unroll
    for (int nf = 0; nf < 4; ++nf) accv[nf] = (f32x4){0.f, 0.f, 0.f, 0.f};
    float ls[4] = {0.f, 0.f, 0.f, 0.f};

    for (int jt = 0; jt <= it; ++jt) {
        const int cur = jt & 1;
        if (jt < it) stageKV(jt + 1, cur ^ 1);

        const bool near = (jt >= it - 1);
        #pragma unroll
        for (int nf = 0; nf < 4; ++nf) {
            f32x4 c = (f32x4){0.f, 0.f, 0.f, 0.f};
            const int jrow = nf * 16 + l15;
            const bf16x8 bk0 = *reinterpret_cast<const bf16x8*>(
                (const char*)Ks[cur] + jrow * 128 + ((l4 * 16) ^ swl));
            const bf16x8 bk1 = *reinterpret_cast<const bf16x8*>(
                (const char*)Ks[cur] + jrow * 128 + ((64 + l4 * 16) ^ swl));
            c = __builtin_amdgcn_mfma_f32_16x16x32_bf16(aq[0], bk0, c, 0, 0, 0);
            c = __builtin_amdgcn_mfma_f32_16x16x32_bf16(aq[1], bk1, c, 0, 0, 0);
            const int j = jt * 64 + nf * 16 + l15;
            #pragma unroll
            for (int r = 0; r < 4; ++r) {
                float pp;
                if (near) {
                    const int i = it * 64 + rbase + r;
                    const int rel = i - j;
                    if (rel < 0) pp = 0.0f;
                    else {
                        const int rc = rel < 9 ? rel : 9;
                        pp = exp2f(fmaf(c[r], SC, qpk_sh[(rbase + r) * 16 + rc]));
                        if (rel < 9) pdiag[(rbase + r) * 9 + rel] = pp;
                    }
                } else {
                    pp = exp2f(fmaf(c[r], SC, q9[r]));
                }
                ls[r] += pp;
                Pl[w * 1152 + (rloc + r) * 72 + nf * 16 + l15] = f2bf(pp);
            }
        }
        #pragma unroll
        for (int ks = 0; ks < 2; ++ks) {
            const bf16x8 pa = *reinterpret_cast<const bf16x8*>(
                &Pl[w * 1152 + l15 * 72 + ks * 32 + 8 * l4]);
            #pragma unroll
            for (int nf = 0; nf < 4; ++nf) {
                const int d = nf * 16 + l15;
                const bf16x8 bv = *reinterpret_cast<const bf16x8*>(
                    (const char*)Vts[cur] + d * 144 + nf * 32 + ks * 64 + l4 * 16);
                accv[nf] = __builtin_amdgcn_mfma_f32_16x16x32_bf16(pa, bv, accv[nf], 0, 0, 0);
            }
        }
        __syncthreads();
    }

    #pragma unroll
    for (int m = 1; m < 16; m <<= 1) {
        #pragma unroll
        for (int r = 0; r < 4; ++r) ls[r] += __shfl_xor(ls[r], m, 64);
    }

    #pragma unroll
    for (int r = 0; r < 4; ++r) {
        const int rowl = rbase + r;
        const float inv = 1.0f / ls[r];
        #pragma unroll
        for (int nf = 0; nf < 4; ++nf) {
            const int col = nf * 16 + l15;
            const float pv9 = pv_sh[9 * 64 + col];
            float extra = ls[r] * pv9;
            #pragma unroll
            for (int rr = 0; rr < 9; ++rr)
                extra += pdiag[rowl * 9 + rr] * (pv_sh[rr * 64 + col] - pv9);
            merged[boff + (size_t)(it * 64 + rowl) * E_ + col] =
                f2bf((accv[nf][r] + extra) * inv);
        }
    }
}

// ---------------- last O-proj + final dot: grid (128, 4)
__global__ __launch_bounds__(256) void o1final_kernel(
    const short* __restrict__ mgb, const short* __restrict__ Wt7,
    const float* __restrict__ bo1, const float* __restrict__ outf,
    const float* __restrict__ fw, float* __restrict__ y)
{
    __shared__ __align__(16) short As[64 * 256];
    __shared__ __align__(16) short Bs[64 * 256];
    const int bm = blockIdx.x, bn = blockIdx.y;
    const int tid = threadIdx.x;
    const int lane = tid & 63, w = tid >> 6;
    const int l15 = lane & 15, l4 = lane >> 4;

    stage_tile((const char*)mgb + (size_t)bm * 32768, (char*)As, w, lane);
    stage_tile((const char*)Wt7 + (size_t)bn * 32768, (char*)Bs, w, lane);
    __syncthreads();

    f32x4 acc[4];
    gemm_compute(As, Bs, acc, w, l15, l4);

    float s[4] = {0.f, 0.f, 0.f, 0.f};
    #pragma unroll
    for (int nf = 0; nf < 4; ++nf) {
        const int col = bn * 64 + nf * 16 + l15;
        const float bb = bo1[col];
        const float fwv = fw[col];
        #pragma unroll
        for (int reg = 0; reg < 4; ++reg) {
            const int rowg = bm * 64 + w * 16 + l4 * 4 + reg;
            const float o = outf[(size_t)rowg * E_ + col] + fmaxf(acc[nf][reg] + bb, 0.0f);
            s[reg] += o * fwv;
        }
    }
    #pragma unroll
    for (int m = 1; m < 16; m <<= 1) {
        #pragma unroll
        for (int reg = 0; reg < 4; ++reg) s[reg] += __shfl_xor(s[reg], m, 64);
    }
    if (l15 == 0) {
        #pragma unroll
        for (int reg = 0; reg < 4; ++reg)
            atomicAdd(&y[bm * 64 + w * 16 + l4 * 4 + reg], s[reg]);
    }
}

extern "C" void kernel_launch(void* const* d_in, const int* in_sizes, int n_in,
                              void* d_out, int out_size, void* d_ws, size_t ws_size,
                              hipStream_t stream) {
    const int*   item_inputs = (const int*)d_in[0];
    const int*   item_ids    = (const int*)d_in[1];
    const float* input_embed = (const float*)d_in[2];
    const float* query_embed = (const float*)d_in[3];
    const float* pos_key     = (const float*)d_in[4];
    const float* pos_value   = (const float*)d_in[5];
    const float* Wq = (const float*)d_in[6];
    const float* bq = (const float*)d_in[7];
    const float* Wk = (const float*)d_in[8];
    const float* bk = (const float*)d_in[9];
    const float* Wv = (const float*)d_in[10];
    const float* bv = (const float*)d_in[11];
    const float* Wo = (const float*)d_in[12];
    const float* bo = (const float*)d_in[13];
    const float* out_w = (const float*)d_in[14];
    const float* out_b = (const float*)d_in[15];
    float* y = (float*)d_out;

    char* w8 = (char*)d_ws;
    float* outf = (float*)(w8);                          // 8 MB f32 hidden (written by o0)
    short* outb = (short*)(w8 + ((size_t)8  << 20));     // 4 MB bf16 hidden
    short* qbb  = (short*)(w8 + ((size_t)12 << 20));     // 4 MB bf16 q-base
    short* Qb   = (short*)(w8 + ((size_t)16 << 20));     // 12 MB bf16 Q,K,V
    short* mgb  = (short*)(w8 + ((size_t)28 << 20));     // 4 MB bf16 merged
    short* Wt   = (short*)(w8 + ((size_t)32 << 20));     // 1 MB bf16 weights^T
    short* Qb1  = (short*)(w8 + ((size_t)34 << 20));     // 4 MB bf16 Q (layer 1)

    setup_kernel<<<641, 256, 0, stream>>>(
        item_inputs, item_ids, input_embed, query_embed,
        Wq, Wk, Wv, Wo, out_b, outb, qbb, Wt, y);

    qkv0_kernel<<<dim3(128, 4, 4), 256, 0, stream>>>(
        qbb, outb, Wt, bq, bk, bv, bq + E_, Qb, Qb1);
    attn_kernel<<<512, 256, 0, stream>>>(
        Qb, Qb + HS_, Qb + 2 * HS_, pos_key, pos_value, mgb);
    o0_kernel<<<dim3(128, 4), 256, 0, stream>>>(
        mgb, Wt + (size_t)3 * 65536, bo, item_inputs, input_embed, outf, outb);

    kv1_kernel<<<dim3(128, 4, 2), 256, 0, stream>>>(
        outb, Wt + (size_t)4 * 65536, bk + E_, bv + E_, Qb);
    attn_kernel<<<512, 256, 0, stream>>>(
        Qb1, Qb + HS_, Qb + 2 * HS_, pos_key, pos_value, mgb);
    o1final_kernel<<<dim3(128, 4), 256, 0, stream>>>(
        mgb, Wt + (size_t)7 * 65536, bo + E_, outf, out_w, y);
}